// Round 10
// baseline (175.489 us; speedup 1.0000x reference)
//
#include <hip/hip_runtime.h>

// CenterShift: out[n,o] = x[n] * (celu(celu((pos_j-pos_i)@w11+b11)@w12+b12) @ w13 + b13)[o]
// N = 2097152, dims 3 -> 16 -> 64 -> 64, fp32 in/out.
//
// Round 10 = r9 (146us: tile loop + contiguous bounce stores) + MFMA layer-2
// done WITHOUT the r3/r5/r6 redundancy: layer 1 stays lane=own-point (1x pos
// load, 1x h1 compute), h1 is transposed through a 3KB LDS buffer that
// time-shares the r9 4KB bounce region (DS pipe is in-order per wave ->
// write/read/write sequences on aliased regions are safe), then layer 2 runs
// as 16 mfma_f32_16x16x32_f16 per wave-tile using the r6-verified A-fragment,
// D-layout and swizzled h2-write mappings verbatim.
// Chip-wide VALU drops ~37us -> ~16us; stores/epilogue unchanged from r9.
//  - a2: A[row=u2*16+r16][k=g*8+j], k>=16 zero (K padded); B-frag read from
//    h1 LDS rows; g>=2 lanes re-read g&1 data (finite, killed by zero A).
//  - bias b12 via persistent C-init regs (r5-verified); b13 reloaded as
//    float4 per use (r6-verified) to keep VGPR <= ~128.
//  - h2 write: byte = pt*128 + (u2*32+g*8) ^ ((pt&7)<<4)  [r6 verbatim]
//  - layer 3 + bounce + contiguous 1KB-per-instr stores  [r9 verbatim]

typedef __attribute__((ext_vector_type(8))) _Float16 f16x8;
typedef __attribute__((ext_vector_type(4))) float f32x4;

#define TILES 4

__device__ __forceinline__ float celu1(float a) {
    return a > 0.0f ? a : __expf(a) - 1.0f;
}

__global__ __launch_bounds__(256) void centershift_kernel(
    const float* __restrict__ x,
    const float* __restrict__ pos_i,
    const float* __restrict__ pos_j,
    const float* __restrict__ w11, const float* __restrict__ b11,
    const float* __restrict__ w12, const float* __restrict__ b12,
    const float* __restrict__ w13, const float* __restrict__ b13,
    float* __restrict__ out, int n)
{
    __shared__ __align__(16) _Float16 h2s[4][64 * 64];  // 8 KB/wave, swizzled
    __shared__ __align__(16) char     aux[4][4096];     // h1 transpose (3KB) +
                                                        // f32 bounce (4KB), time-shared

    const int lane = threadIdx.x & 63;
    const int wid  = threadIdx.x >> 6;
    const int g    = lane >> 4;    // 16-lane group 0..3
    const int r16  = lane & 15;
    const int swzR = (r16 & 7) << 4;

    const int wbase = (blockIdx.x * 4 + wid) * (64 * TILES);
    if (wbase >= n) return;

    char* h2b  = (char*)&h2s[wid][0];
    char* auxb = (char*)&aux[wid][0];

    // ---- hoisted fragments (issue first; overlap tile-0 compute) ----
    // layer-3 A = w13^T: A[row = u*16 + r16][k = kh*32 + g*8 + j]   [r9 verbatim]
    f16x8 a3[4][2];
#pragma unroll
    for (int u = 0; u < 4; ++u)
#pragma unroll
        for (int kh = 0; kh < 2; ++kh) {
            f16x8 v;
#pragma unroll
            for (int j = 0; j < 8; ++j)
                v[j] = (_Float16)w13[(kh * 32 + g * 8 + j) * 64 + u * 16 + r16];
            a3[u][kh] = v;
        }
    // layer-2 A = w12^T, K zero-padded 16->32   [r5/r6 verbatim, no bias slot]
    f16x8 a2[4];
#pragma unroll
    for (int u2 = 0; u2 < 4; ++u2) {
        f16x8 v;
#pragma unroll
        for (int j = 0; j < 8; ++j) {
            const int k = g * 8 + j;
            v[j] = (k < 16) ? (_Float16)w12[k * 64 + u2 * 16 + r16] : (_Float16)0.0f;
        }
        a2[u2] = v;
    }
    // layer-2 bias in C/D layout (persistent): lane holds o = u2*16 + g*4 + rr
    float b2v[4][4];
#pragma unroll
    for (int u2 = 0; u2 < 4; ++u2) {
        const float4 bv = *reinterpret_cast<const float4*>(b12 + u2 * 16 + g * 4);
        b2v[u2][0] = bv.x; b2v[u2][1] = bv.y; b2v[u2][2] = bv.z; b2v[u2][3] = bv.w;
    }

    // ---- preload tile-0 pos (lane = its own point) ----
    const float* pip = pos_i + 3 * (size_t)(wbase + lane);
    const float* pjp = pos_j + 3 * (size_t)(wbase + lane);
    float3 cpi = *reinterpret_cast<const float3*>(pip);
    float3 cpj = *reinterpret_cast<const float3*>(pjp);

#pragma unroll 1
    for (int t = 0; t < TILES; ++t) {
        const int tb = wbase + t * 64;
        if (tb >= n) break;

        const float p0 = cpj.x - cpi.x, p1 = cpj.y - cpi.y, p2 = cpj.z - cpi.z;

        // ---- layer 1: 3 -> 16 (own point), pack f16, stage for transpose ----
        float h1[16];
#pragma unroll
        for (int j = 0; j < 16; ++j) {
            float a = b11[j];
            a = fmaf(p0, w11[j], a);
            a = fmaf(p1, w11[16 + j], a);
            a = fmaf(p2, w11[32 + j], a);
            h1[j] = celu1(a);
        }
        {
            f16x8 hp0, hp1;
#pragma unroll
            for (int j = 0; j < 8; ++j) { hp0[j] = (_Float16)h1[j]; hp1[j] = (_Float16)h1[8 + j]; }
            // row stride 48B (16-aligned, 12-bank stagger)
            *reinterpret_cast<f16x8*>(auxb + lane * 48)      = hp0;
            *reinterpret_cast<f16x8*>(auxb + lane * 48 + 16) = hp1;
        }

        // prefetch next tile's pos (hidden under the compute below)
        if (t + 1 < TILES) {
            cpi = *reinterpret_cast<const float3*>(pip + (t + 1) * 192);
            cpj = *reinterpret_cast<const float3*>(pjp + (t + 1) * 192);
        }

        // ---- layer 2: MFMA over four 16-point tiles -> swizzled h2 LDS ----
#pragma unroll
        for (int tt = 0; tt < 4; ++tt) {
            const int pt = tt * 16 + r16;
            // B[k=g*8+j][col=r16] = h1[(g&1)*8+j] of point pt; g>=2 lanes
            // re-read the g&1 slice (finite data, zeroed by A's K-pad).
            const f16x8 bfrag = *reinterpret_cast<const f16x8*>(auxb + pt * 48 + (g & 1) * 16);
#pragma unroll
            for (int u2 = 0; u2 < 4; ++u2) {
                f32x4 acc = { b2v[u2][0], b2v[u2][1], b2v[u2][2], b2v[u2][3] };
                acc = __builtin_amdgcn_mfma_f32_16x16x32_f16(a2[u2], bfrag, acc, 0, 0, 0);
                union { _Float16 h[4]; unsigned long long v; } pk;
                pk.h[0] = (_Float16)celu1(acc[0]);
                pk.h[1] = (_Float16)celu1(acc[1]);
                pk.h[2] = (_Float16)celu1(acc[2]);
                pk.h[3] = (_Float16)celu1(acc[3]);
                // h2[pt][o = u2*16 + g*4 + 0..3]  [r6 verbatim]
                const int byteoff = pt * 128 + u2 * 32 + g * 8;
                *reinterpret_cast<unsigned long long*>(h2b + (byteoff ^ swzR)) = pk.v;
            }
        }

        // ---- layer 3: MFMA -> f32 bounce -> contiguous 1KB-per-instr stores ----
        // [r9 verbatim; bounce aliases the h1 region -- DS in-order per wave]
#pragma unroll
        for (int t2 = 0; t2 < 4; ++t2) {
            const int pt   = t2 * 16 + r16;
            const int rowR = pt * 128;
            const f16x8 bb0 = *reinterpret_cast<const f16x8*>(h2b + (rowR + ((     g * 16) ^ swzR)));
            const f16x8 bb1 = *reinterpret_cast<const f16x8*>(h2b + (rowR + ((64 + g * 16) ^ swzR)));
            const float xvt = x[tb + pt];          // 1 line, L1 broadcast
#pragma unroll
            for (int u = 0; u < 4; ++u) {
                const float4 bias = *reinterpret_cast<const float4*>(b13 + u * 16 + g * 4);
                f32x4 acc = { bias.x, bias.y, bias.z, bias.w };
                acc = __builtin_amdgcn_mfma_f32_16x16x32_f16(a3[u][0], bb0, acc, 0, 0, 0);
                acc = __builtin_amdgcn_mfma_f32_16x16x32_f16(a3[u][1], bb1, acc, 0, 0, 0);
                float4 o4 = { acc[0] * xvt, acc[1] * xvt, acc[2] * xvt, acc[3] * xvt };
                const int wb = r16 * 256 + ((u * 64 + g * 16) ^ ((r16 & 7) << 4));
                *reinterpret_cast<float4*>(auxb + wb) = o4;
            }
            // drain: 4 instructions, each one contiguous 1KB chunk (fill pattern)
            float* og = out + (size_t)(tb + t2 * 16) * 64;
#pragma unroll
            for (int k = 0; k < 4; ++k) {
                const int ptl = k * 4 + (lane >> 4);   // local point 0..15
                const int c   = lane & 15;             // 16B channel block
                const int rb  = ptl * 256 + ((c * 16) ^ ((ptl & 7) << 4));
                const float4 v = *reinterpret_cast<const float4*>(auxb + rb);
                *reinterpret_cast<float4*>(og + k * 256 + lane * 4) = v;
            }
        }
    }
}

extern "C" void kernel_launch(void* const* d_in, const int* in_sizes, int n_in,
                              void* d_out, int out_size, void* d_ws, size_t ws_size,
                              hipStream_t stream) {
    const float* x     = (const float*)d_in[0];
    const float* pos_i = (const float*)d_in[1];
    const float* pos_j = (const float*)d_in[2];
    const float* w11   = (const float*)d_in[3];
    const float* b11   = (const float*)d_in[4];
    const float* w12   = (const float*)d_in[5];
    const float* b12   = (const float*)d_in[6];
    const float* w13   = (const float*)d_in[7];
    const float* b13   = (const float*)d_in[8];
    float* out = (float*)d_out;

    const int n = in_sizes[0];                        // N (x is [N,1])
    const int per_block = 256 * TILES;                // 4 waves x 4 tiles x 64 pts
    const int blocks = (n + per_block - 1) / per_block;
    centershift_kernel<<<blocks, 256, 0, stream>>>(
        x, pos_i, pos_j, w11, b11, w12, b12, w13, b13, out, n);
}

// Round 11
// 160.769 us; speedup vs baseline: 1.0916x; 1.0916x over previous
//
#include <hip/hip_runtime.h>

// CenterShift: out[n,o] = x[n] * (celu(celu((pos_j-pos_i)@w11+b11)@w12+b12) @ w13 + b13)[o]
// N = 2097152, dims 3 -> 16 -> 64 -> 64, fp32 in/out.
//
// Round 11 = r9 (146us, the measured best) with the LDS footprint halved:
//  - SCALAR layer-2 is final (MFMA-l2 lost 4x: r3/r5/r6/r10).
//  - After the 8 swizzled h2 writes, ALL 8 layer-3 B-fragments are preloaded
//    into registers (bb[4][2], 32 VGPR). The h2 slice is then dead, so the
//    f32 store-bounce time-shares it (ping-pong 2x4KB halves). DS pipe is
//    in-order per wave -> aliasing write/read/write sequences are safe
//    (same property r9/r10 relied on). The separate 16KB aux array is GONE:
//    LDS 48 -> 32 KB/block -> 4-5 blocks/CU (12 -> 16-20 waves/CU).
//  - Manual software pipeline in layer 3: drain (bounce-read + 1KB-contiguous
//    stores) of group t2-1 issues during MFMA of group t2 -> DS latency and
//    store issue hidden under compute.
//  - Everything else r9 verbatim: 4-tile loop, pos prefetch, hoisted a3/b3v,
//    contiguous 1KB-per-instruction stores, no __syncthreads.

typedef __attribute__((ext_vector_type(8))) _Float16 f16x8;
typedef __attribute__((ext_vector_type(4))) float f32x4;

#define TILES 4

__device__ __forceinline__ float celu1(float a) {
    return a > 0.0f ? a : __expf(a) - 1.0f;
}

__global__ __launch_bounds__(256) void centershift_kernel(
    const float* __restrict__ x,
    const float* __restrict__ pos_i,
    const float* __restrict__ pos_j,
    const float* __restrict__ w11, const float* __restrict__ b11,
    const float* __restrict__ w12, const float* __restrict__ b12,
    const float* __restrict__ w13, const float* __restrict__ b13,
    float* __restrict__ out, int n)
{
    // 8 KB per wave: h2 tile during layers 1-2, f32 bounce during layer 3
    __shared__ __align__(16) _Float16 h2s[4][4096];   // 32 KB/block

    const int lane = threadIdx.x & 63;
    const int wid  = threadIdx.x >> 6;
    const int g    = lane >> 4;    // 16-lane group 0..3
    const int r16  = lane & 15;
    const int swzR = (r16 & 7) << 4;

    const int wbase = (blockIdx.x * 4 + wid) * (64 * TILES);
    if (wbase >= n) return;

    char* h2b = (char*)&h2s[wid][0];

    // ---- hoisted fragments (issue first; overlap tile-0 compute) ----
    // layer-3 A = w13^T: A[row = u*16 + r16][k = kh*32 + g*8 + j]   [r9 verbatim]
    f16x8 a3[4][2];
#pragma unroll
    for (int u = 0; u < 4; ++u)
#pragma unroll
        for (int kh = 0; kh < 2; ++kh) {
            f16x8 v;
#pragma unroll
            for (int j = 0; j < 8; ++j)
                v[j] = (_Float16)w13[(kh * 32 + g * 8 + j) * 64 + u * 16 + r16];
            a3[u][kh] = v;
        }
    // layer-3 bias in C/D layout: lane holds o = u*16 + g*4 + rr
    float b3v[4][4];
#pragma unroll
    for (int u = 0; u < 4; ++u) {
        const float4 bv = *reinterpret_cast<const float4*>(b13 + u * 16 + g * 4);
        b3v[u][0] = bv.x; b3v[u][1] = bv.y; b3v[u][2] = bv.z; b3v[u][3] = bv.w;
    }

    // ---- preload tile-0 pos (lane = its own point) ----
    const float* pip = pos_i + 3 * (size_t)(wbase + lane);
    const float* pjp = pos_j + 3 * (size_t)(wbase + lane);
    float3 cpi = *reinterpret_cast<const float3*>(pip);
    float3 cpj = *reinterpret_cast<const float3*>(pjp);

    const int swzW = (lane & 7) << 4;
    const int rowW = lane * 128;

#pragma unroll 1
    for (int t = 0; t < TILES; ++t) {
        const int tb = wbase + t * 64;
        if (tb >= n) break;

        const float p0 = cpj.x - cpi.x, p1 = cpj.y - cpi.y, p2 = cpj.z - cpi.z;

        // ---- layer 1: 3 -> 16 ----
        float h1[16];
#pragma unroll
        for (int j = 0; j < 16; ++j) {
            float a = b11[j];
            a = fmaf(p0, w11[j], a);
            a = fmaf(p1, w11[16 + j], a);
            a = fmaf(p2, w11[32 + j], a);
            h1[j] = celu1(a);
        }

        // prefetch next tile's pos (hidden under the compute below)
        if (t + 1 < TILES) {
            cpi = *reinterpret_cast<const float3*>(pip + (t + 1) * 192);
            cpj = *reinterpret_cast<const float3*>(pjp + (t + 1) * 192);
        }

        // ---- layer 2: 16 -> 64 scalar (wave-uniform weights -> s_load),
        //      streamed to swizzled h2 LDS in f16x8 chunks  [r9 verbatim] ----
        for (int c = 0; c < 8; ++c) {
            f16x8 v;
#pragma unroll
            for (int j = 0; j < 8; ++j) {
                const int o = c * 8 + j;
                float a = b12[o];
#pragma unroll
                for (int k = 0; k < 16; ++k)
                    a = fmaf(h1[k], w12[k * 64 + o], a);
                v[j] = (_Float16)celu1(a);
            }
            *reinterpret_cast<f16x8*>(h2b + (rowW + ((c * 16) ^ swzW))) = v;
        }

        // ---- preload ALL layer-3 B fragments (h2 slice dead afterwards) ----
        f16x8 bb[4][2];
#pragma unroll
        for (int t2 = 0; t2 < 4; ++t2) {
            const int rowR = (t2 * 16 + r16) * 128;
            bb[t2][0] = *reinterpret_cast<const f16x8*>(h2b + (rowR + ((     g * 16) ^ swzR)));
            bb[t2][1] = *reinterpret_cast<const f16x8*>(h2b + (rowR + ((64 + g * 16) ^ swzR)));
        }

        // ---- layer 3, software-pipelined: MFMA(t2) + bounce-write(t2),
        //      then drain(t2-1) [bounce-read + contiguous 1KB stores].
        //      Bounce ping-pongs between the two 4KB halves of the h2 slice. ----
#pragma unroll
        for (int t2 = 0; t2 < 4; ++t2) {
            const int pt   = t2 * 16 + r16;
            const int half = (t2 & 1) * 4096;
            const float xvt = x[tb + pt];          // 1 line, L1 broadcast
#pragma unroll
            for (int u = 0; u < 4; ++u) {
                f32x4 acc = { b3v[u][0], b3v[u][1], b3v[u][2], b3v[u][3] };
                acc = __builtin_amdgcn_mfma_f32_16x16x32_f16(a3[u][0], bb[t2][0], acc, 0, 0, 0);
                acc = __builtin_amdgcn_mfma_f32_16x16x32_f16(a3[u][1], bb[t2][1], acc, 0, 0, 0);
                float4 o4 = { acc[0] * xvt, acc[1] * xvt, acc[2] * xvt, acc[3] * xvt };
                const int wb = half + r16 * 256 + ((u * 64 + g * 16) ^ ((r16 & 7) << 4));
                *reinterpret_cast<float4*>(h2b + wb) = o4;
            }
            if (t2 > 0) {   // drain previous group while this group's writes land
                const int ph = ((t2 - 1) & 1) * 4096;
                float* og = out + (size_t)(tb + (t2 - 1) * 16) * 64;
#pragma unroll
                for (int k = 0; k < 4; ++k) {
                    const int ptl = k * 4 + (lane >> 4);
                    const int c   = lane & 15;
                    const int rb  = ph + ptl * 256 + ((c * 16) ^ ((ptl & 7) << 4));
                    const float4 v = *reinterpret_cast<const float4*>(h2b + rb);
                    *reinterpret_cast<float4*>(og + k * 256 + lane * 4) = v;
                }
            }
        }
        {   // tail drain: group 3
            float* og = out + (size_t)(tb + 3 * 16) * 64;
#pragma unroll
            for (int k = 0; k < 4; ++k) {
                const int ptl = k * 4 + (lane >> 4);
                const int c   = lane & 15;
                const int rb  = 4096 + ptl * 256 + ((c * 16) ^ ((ptl & 7) << 4));
                const float4 v = *reinterpret_cast<const float4*>(h2b + rb);
                *reinterpret_cast<float4*>(og + k * 256 + lane * 4) = v;
            }
        }
    }
}

extern "C" void kernel_launch(void* const* d_in, const int* in_sizes, int n_in,
                              void* d_out, int out_size, void* d_ws, size_t ws_size,
                              hipStream_t stream) {
    const float* x     = (const float*)d_in[0];
    const float* pos_i = (const float*)d_in[1];
    const float* pos_j = (const float*)d_in[2];
    const float* w11   = (const float*)d_in[3];
    const float* b11   = (const float*)d_in[4];
    const float* w12   = (const float*)d_in[5];
    const float* b12   = (const float*)d_in[6];
    const float* w13   = (const float*)d_in[7];
    const float* b13   = (const float*)d_in[8];
    float* out = (float*)d_out;

    const int n = in_sizes[0];                        // N (x is [N,1])
    const int per_block = 256 * TILES;                // 4 waves x 4 tiles x 64 pts
    const int blocks = (n + per_block - 1) / per_block;
    centershift_kernel<<<blocks, 256, 0, stream>>>(
        x, pos_i, pos_j, w11, b11, w12, b12, w13, b13, out, n);
}

// Round 12
// 158.186 us; speedup vs baseline: 1.1094x; 1.0163x over previous
//
#include <hip/hip_runtime.h>

// CenterShift: out[n,o] = x[n] * (celu(celu((pos_j-pos_i)@w11+b11)@w12+b12) @ w13 + b13)[o]
// N = 2097152, dims 3 -> 16 -> 64 -> 64, fp32 in/out.
//
// Round 12 = r9 (146us best) with ONE change: the f32 bounce buffer is
// replaced by an f16 bounce aliased into the just-consumed h2 rows.
//  - After group t2's two bb ds_reads, its 16 h2 rows (16x128B f16 = 2KB) are
//    dead; the group's output (16 pts x 64 ch f16 = 2KB) is bounced in-place.
//    DS pipe is in-order per wave -> read-before-write on the same rows is
//    safe (the property r9/r10/r11 relied on).
//  - Separate bounce array GONE: LDS 48 -> 32 KB/block -> 4-5 blocks/CU
//    (12 -> 16-20 waves/CU), with ZERO new persistent VGPRs (r11's mistake).
//  - Output rounds through f16 once: +~0.002 absmax (0.0156 -> ~0.018,
//    threshold 0.098).
//  - Everything else r9 verbatim: scalar layer-2 (final; MFMA-l2 lost 4x),
//    4-tile loop, pos prefetch, hoisted a3/b3v, swizzled h2, contiguous
//    1KB-per-instruction stores, per-wave LDS, no __syncthreads.

typedef __attribute__((ext_vector_type(8))) _Float16 f16x8;
typedef __attribute__((ext_vector_type(4))) float f32x4;

#define TILES 4

__device__ __forceinline__ float celu1(float a) {
    return a > 0.0f ? a : __expf(a) - 1.0f;
}

__global__ __launch_bounds__(256) void centershift_kernel(
    const float* __restrict__ x,
    const float* __restrict__ pos_i,
    const float* __restrict__ pos_j,
    const float* __restrict__ w11, const float* __restrict__ b11,
    const float* __restrict__ w12, const float* __restrict__ b12,
    const float* __restrict__ w13, const float* __restrict__ b13,
    float* __restrict__ out, int n)
{
    // 8 KB per wave: h2 tile, with per-group in-place f16 bounce during layer 3
    __shared__ __align__(16) _Float16 h2s[4][4096];   // 32 KB/block

    const int lane = threadIdx.x & 63;
    const int wid  = threadIdx.x >> 6;
    const int g    = lane >> 4;    // 16-lane group 0..3
    const int r16  = lane & 15;
    const int swzR = (r16 & 7) << 4;

    const int wbase = (blockIdx.x * 4 + wid) * (64 * TILES);
    if (wbase >= n) return;

    char* h2b = (char*)&h2s[wid][0];

    // ---- hoisted fragments (issue first; overlap tile-0 compute) [r9 verbatim] ----
    // layer-3 A = w13^T: A[row = u*16 + r16][k = kh*32 + g*8 + j]
    f16x8 a3[4][2];
#pragma unroll
    for (int u = 0; u < 4; ++u)
#pragma unroll
        for (int kh = 0; kh < 2; ++kh) {
            f16x8 v;
#pragma unroll
            for (int j = 0; j < 8; ++j)
                v[j] = (_Float16)w13[(kh * 32 + g * 8 + j) * 64 + u * 16 + r16];
            a3[u][kh] = v;
        }
    // layer-3 bias in C/D layout: lane holds o = u*16 + g*4 + rr
    float b3v[4][4];
#pragma unroll
    for (int u = 0; u < 4; ++u) {
        const float4 bv = *reinterpret_cast<const float4*>(b13 + u * 16 + g * 4);
        b3v[u][0] = bv.x; b3v[u][1] = bv.y; b3v[u][2] = bv.z; b3v[u][3] = bv.w;
    }

    // ---- preload tile-0 pos (lane = its own point) ----
    const float* pip = pos_i + 3 * (size_t)(wbase + lane);
    const float* pjp = pos_j + 3 * (size_t)(wbase + lane);
    float3 cpi = *reinterpret_cast<const float3*>(pip);
    float3 cpj = *reinterpret_cast<const float3*>(pjp);

    const int swzW = (lane & 7) << 4;
    const int rowW = lane * 128;

#pragma unroll 1
    for (int t = 0; t < TILES; ++t) {
        const int tb = wbase + t * 64;
        if (tb >= n) break;

        const float p0 = cpj.x - cpi.x, p1 = cpj.y - cpi.y, p2 = cpj.z - cpi.z;

        // ---- layer 1: 3 -> 16 ----
        float h1[16];
#pragma unroll
        for (int j = 0; j < 16; ++j) {
            float a = b11[j];
            a = fmaf(p0, w11[j], a);
            a = fmaf(p1, w11[16 + j], a);
            a = fmaf(p2, w11[32 + j], a);
            h1[j] = celu1(a);
        }

        // prefetch next tile's pos (hidden under the compute below)
        if (t + 1 < TILES) {
            cpi = *reinterpret_cast<const float3*>(pip + (t + 1) * 192);
            cpj = *reinterpret_cast<const float3*>(pjp + (t + 1) * 192);
        }

        // ---- layer 2: 16 -> 64 scalar (wave-uniform weights -> s_load),
        //      streamed to swizzled h2 LDS in f16x8 chunks  [r9 verbatim] ----
        for (int c = 0; c < 8; ++c) {
            f16x8 v;
#pragma unroll
            for (int j = 0; j < 8; ++j) {
                const int o = c * 8 + j;
                float a = b12[o];
#pragma unroll
                for (int k = 0; k < 16; ++k)
                    a = fmaf(h1[k], w12[k * 64 + o], a);
                v[j] = (_Float16)celu1(a);
            }
            *reinterpret_cast<f16x8*>(h2b + (rowW + ((c * 16) ^ swzW))) = v;
        }

        // ---- layer 3: per 16-point group: bb reads -> MFMA -> in-place f16
        //      bounce into the group's own (now dead) h2 rows -> drain as
        //      contiguous 1KB-per-instruction stores  ----
#pragma unroll
        for (int t2 = 0; t2 < 4; ++t2) {
            const int pt    = t2 * 16 + r16;
            const int rowR  = pt * 128;
            const int gbase = t2 * 2048;           // group's 16 rows (2 KB)
            const f16x8 bb0 = *reinterpret_cast<const f16x8*>(h2b + (rowR + ((     g * 16) ^ swzR)));
            const f16x8 bb1 = *reinterpret_cast<const f16x8*>(h2b + (rowR + ((64 + g * 16) ^ swzR)));
            const float xvt = x[tb + pt];          // 1 line, L1 broadcast
#pragma unroll
            for (int u = 0; u < 4; ++u) {
                f32x4 acc = { b3v[u][0], b3v[u][1], b3v[u][2], b3v[u][3] };
                acc = __builtin_amdgcn_mfma_f32_16x16x32_f16(a3[u][0], bb0, acc, 0, 0, 0);
                acc = __builtin_amdgcn_mfma_f32_16x16x32_f16(a3[u][1], bb1, acc, 0, 0, 0);
                // pack final f32 -> f16 (adds <= ~0.002 abs err; budget OK)
                union { _Float16 h[4]; unsigned long long v; } pk;
                pk.h[0] = (_Float16)(acc[0] * xvt);
                pk.h[1] = (_Float16)(acc[1] * xvt);
                pk.h[2] = (_Float16)(acc[2] * xvt);
                pk.h[3] = (_Float16)(acc[3] * xvt);
                // bounce byte (within group): row r16, ch0 = u*16+g*4 ->
                // off = u*32+g*8, XOR-swizzled by (r16&15)<<3 (bijective,
                // min-phase b64: 16 bank-pairs x 4 lanes)
                const int wb = gbase + r16 * 128 + ((u * 32 + g * 8) ^ ((r16 & 15) << 3));
                *reinterpret_cast<unsigned long long*>(h2b + wb) = pk.v;
            }
            // drain: 4 instructions, each one contiguous 1KB chunk (fill pattern)
            float* og = out + (size_t)(tb + t2 * 16) * 64;
#pragma unroll
            for (int k = 0; k < 4; ++k) {
                const int ptl = k * 4 + (lane >> 4);   // local point 0..15
                const int rb  = gbase + ptl * 128 + (((lane & 15) * 8) ^ ((ptl & 15) << 3));
                union { _Float16 h[4]; unsigned long long v; } pk;
                pk.v = *reinterpret_cast<const unsigned long long*>(h2b + rb);
                float4 v4 = { (float)pk.h[0], (float)pk.h[1], (float)pk.h[2], (float)pk.h[3] };
                *reinterpret_cast<float4*>(og + k * 256 + lane * 4) = v4;
            }
        }
    }
}

extern "C" void kernel_launch(void* const* d_in, const int* in_sizes, int n_in,
                              void* d_out, int out_size, void* d_ws, size_t ws_size,
                              hipStream_t stream) {
    const float* x     = (const float*)d_in[0];
    const float* pos_i = (const float*)d_in[1];
    const float* pos_j = (const float*)d_in[2];
    const float* w11   = (const float*)d_in[3];
    const float* b11   = (const float*)d_in[4];
    const float* w12   = (const float*)d_in[5];
    const float* b12   = (const float*)d_in[6];
    const float* w13   = (const float*)d_in[7];
    const float* b13   = (const float*)d_in[8];
    float* out = (float*)d_out;

    const int n = in_sizes[0];                        // N (x is [N,1])
    const int per_block = 256 * TILES;                // 4 waves x 4 tiles x 64 pts
    const int blocks = (n + per_block - 1) / per_block;
    centershift_kernel<<<blocks, 256, 0, stream>>>(
        x, pos_i, pos_j, w11, b11, w12, b12, w13, b13, out, n);
}